// Round 5
// baseline (178.069 us; speedup 1.0000x reference)
//
#include <hip/hip_runtime.h>
#include <math.h>

// DecoderLayer: B=4,N=1,S=256,D=128,H=128,DFF=512, fp32 end-to-end.
// Round-14: occupancy 1 -> 2 blocks/CU by halving block work, doubling grid.
// R13 counters: fused=50us @ VALUBusy 33%, Occ 20.9% (grid 256 = 1 blk/CU,
// 2 waves/SIMD), HBM 4.5%, conflicts 0 -> latency-bound, grid-capped.
//  1. proj3: 4 rows/block, grid (256,2)=512 blocks (was 8-row x 256).
//  2. fused_attn12: 2 rows/block, grid 512 (was 4-row x 256). LDS 37KB.
//     Scoring direct-global (R13), mask folded into scoring epilogue,
//     softmax normalize pass folded into AV reduce (rinvS).
// All k-splits deepened to keep 512 threads busy on 2 rows.
// b2 dropped (softmax shift invariance). RES_RATIO=1 -> plain residual add.

#define LN_EPS 1e-6f
#define NEGV  (-1e9f)

constexpr int B = 4, S = 256, D = 128, H = 128, DFF = 512;
constexpr int R = B * S;   // 1024 rows (N=1)

struct P {
    const float *x, *enc, *com_mask, *dec_mask;
    const float *W1q, *W1k, *b1, *W2;
    const float *Ww1, *bw1, *Wd1, *bd1;
    const float *Ww2, *bw2, *Wd2, *bd2;
    const float *Wf1, *bf1, *Wf2, *bf2;
    const float *ln1g, *ln1b, *ln2g, *ln2b, *ln3g, *ln3b;
    float *out;
    float *xw, *qa, *kb, *kv2w, *kb2, *ka2;
};

// ========== 1: chained projections, 4 rows/block, grid (R/4, 2) ==========
__global__ __launch_bounds__(512) void proj3_kernel(P p)
{
    const int g = blockIdx.y, tid = threadIdx.x;
    const int r0 = blockIdx.x * 4;
    __shared__ __align__(16) float Ash[4 * 128];
    __shared__ __align__(16) float Pw[4 * 128];
    __shared__ __align__(16) float Pp[4 * 4 * 128];   // mm1 partials [4kh][4r][128]
    __shared__ __align__(16) float P2[2 * 2 * 4 * 128]; // mm2 partials

    const float* A    = g ? p.enc  : p.x;
    const float* Wp   = g ? p.Ww2  : p.Ww1;
    const float* bp   = g ? p.bw2  : p.bw1;
    float*       o_w  = g ? p.kv2w : p.xw;
    const float* Wsec = g ? p.W1k  : p.W1q;  // kb2 | qa
    const float* bsec = g ? nullptr: p.b1;
    float*       o_s  = g ? p.kb2  : p.qa;
    const float* Wthr = g ? p.W1q  : p.W1k;  // ka2 | kb
    float*       o_t  = g ? p.ka2  : p.kb;

    if (tid < 128)
        ((float4*)Ash)[tid] = ((const float4*)(A + (size_t)r0 * 128))[tid];
    __syncthreads();

    // ---- xw = A@Wp + bp, k-split x4 (32-deep chains) ----
    {
        const int kh = tid >> 7, unit = tid & 127, lr = unit >> 5, c4 = unit & 31;
        const float4* W4 = (const float4*)Wp;
        float4 acc = (kh == 0) ? ((const float4*)bp)[c4] : make_float4(0.f, 0.f, 0.f, 0.f);
        const int k0 = kh * 32;
        #pragma unroll 8
        for (int k = 0; k < 32; ++k) {
            const float a = Ash[lr * 128 + k0 + k];
            const float4 w = W4[(k0 + k) * 32 + c4];
            acc.x = fmaf(a, w.x, acc.x); acc.y = fmaf(a, w.y, acc.y);
            acc.z = fmaf(a, w.z, acc.z); acc.w = fmaf(a, w.w, acc.w);
        }
        ((float4*)Pp)[kh * 128 + unit] = acc;
    }
    __syncthreads();
    if (tid < 128) {
        const int lr = tid >> 5, c4 = tid & 31;
        const float4 a0 = ((const float4*)Pp)[tid];
        const float4 a1 = ((const float4*)Pp)[128 + tid];
        const float4 a2 = ((const float4*)Pp)[256 + tid];
        const float4 a3 = ((const float4*)Pp)[384 + tid];
        const float4 w = make_float4(a0.x + a1.x + a2.x + a3.x,
                                     a0.y + a1.y + a2.y + a3.y,
                                     a0.z + a1.z + a2.z + a3.z,
                                     a0.w + a1.w + a2.w + a3.w);
        ((float4*)Pw)[tid] = w;
        ((float4*)o_w)[(size_t)(r0 + lr) * 32 + c4] = w;
    }
    __syncthreads();

    // ---- {sec,thr} concurrently, each k-split x2 (64-deep) ----
    {
        const int which = tid >> 8, sub = tid & 255;
        const int kh = sub >> 7, unit2 = sub & 127, lr = unit2 >> 5, c4 = unit2 & 31;
        const float* W = which ? Wthr : Wsec;
        const float* bb = which ? nullptr : bsec;
        const float4* W4 = (const float4*)W;
        float4 acc = (kh == 0 && bb) ? ((const float4*)bb)[c4]
                                     : make_float4(0.f, 0.f, 0.f, 0.f);
        const int k0 = kh * 64;
        #pragma unroll 8
        for (int k = 0; k < 64; ++k) {
            const float a = Pw[lr * 128 + k0 + k];
            const float4 w = W4[(k0 + k) * 32 + c4];
            acc.x = fmaf(a, w.x, acc.x); acc.y = fmaf(a, w.y, acc.y);
            acc.z = fmaf(a, w.z, acc.z); acc.w = fmaf(a, w.w, acc.w);
        }
        ((float4*)P2)[(which * 2 + kh) * 128 + unit2] = acc;
    }
    __syncthreads();
    if (tid < 256) {
        const int which = tid >> 7, unit2 = tid & 127;
        const int lr = unit2 >> 5, c4 = unit2 & 31;
        const float4 p0 = ((const float4*)P2)[(which * 2 + 0) * 128 + unit2];
        const float4 p1 = ((const float4*)P2)[(which * 2 + 1) * 128 + unit2];
        float* o = which ? o_t : o_s;
        ((float4*)o)[(size_t)(r0 + lr) * 32 + c4] =
            make_float4(p0.x + p1.x, p0.y + p1.y, p0.z + p1.z, p0.w + p1.w);
    }
}

// ---- scoring: 8 fma/fmax pairs (two relu-dot terms, 4 h-components) ----
#define SC8(ACC, O1, X1, O2, X2)                                               \
    ACC = fmaf(fmaxf((O1).x + (X1).x, 0.f), w.x, ACC);                         \
    ACC = fmaf(fmaxf((O1).y + (X1).y, 0.f), w.y, ACC);                         \
    ACC = fmaf(fmaxf((O1).z + (X1).z, 0.f), w.z, ACC);                         \
    ACC = fmaf(fmaxf((O1).w + (X1).w, 0.f), w.w, ACC);                         \
    ACC = fmaf(fmaxf((O2).x + (X2).x, 0.f), w.x, ACC);                         \
    ACC = fmaf(fmaxf((O2).y + (X2).y, 0.f), w.y, ACC);                         \
    ACC = fmaf(fmaxf((O2).z + (X2).z, 0.f), w.z, ACC);                         \
    ACC = fmaf(fmaxf((O2).w + (X2).w, 0.f), w.w, ACC);

// ====== fused attn stage (2 rows/block) ======
// smem (floats): s8 [0,512) | rowS [512,768) | rinvS [768,784) |
//   qa2L [784,1040) | qb2L [1040,1296) | scratch SB=1296:
//   attn: avp@SB(2048) aoS@SB+2048(256) pp@SB+2304(2048)
//   qproj: qpp@SB(2048) q2wS@SB+2048(256) qp2@SB+2304(2048)
//   ffn: hidP@SB(4096) part@SB+4096(4096)
template<bool FIRST>
__device__ __forceinline__ void attn_stage(const P& p, float* smem,
                                           int tid, int r0, int bS)
{
    float* s8    = smem;          // [2][256] exp(scores - m), unnormalized
    float* rowS  = smem + 512;    // [2][128] LN output
    float* rinvS = smem + 768;    // [2]
    float* qa2L  = smem + 784;    // [2][128]
    float* qb2L  = smem + 1040;   // [2][128]
    constexpr int SB = 1296;

    const float* __restrict__ S1g = FIRST ? p.kb : p.kb2;   // streamed term1
    const float* __restrict__ S2g = FIRST ? p.qa : p.ka2;   // streamed term2
    const float* mask = FIRST ? p.com_mask : p.dec_mask;
    const float* V    = FIRST ? p.xw : p.kv2w;
    const float* Wd   = FIRST ? p.Wd1 : p.Wd2;
    const float* bd   = FIRST ? p.bd1 : p.bd2;
    const float* lg   = FIRST ? p.ln1g : p.ln2g;
    const float* lb   = FIRST ? p.ln1b : p.ln2b;

    // ---------------- scoring (direct-global, mask folded) ----------------
    // s[r,k] = sum_h relu(O1[r,h]+S1[k,h])*W2[h] + relu(O2[r,h]+S2[k,h])*W2[h]
    // thread: hh = tid&7 (h-lane, h = hh*4 + 32j), kk = tid>>3 (0..63).
    {
        const int hh = tid & 7, kk = tid >> 3;
        const int rA = r0, rB = r0 + 1;

        float4 o1A[4], o1B[4], o2A[4], o2B[4], w2r[4];
        #pragma unroll
        for (int j = 0; j < 4; ++j) {
            const int h = hh * 4 + 32 * j;
            if (FIRST) {
                o1A[j] = *(const float4*)(p.qa + (size_t)rA * H + h);
                o1B[j] = *(const float4*)(p.qa + (size_t)rB * H + h);
                o2A[j] = *(const float4*)(p.kb + (size_t)rA * H + h);
                o2B[j] = *(const float4*)(p.kb + (size_t)rB * H + h);
            } else {
                o1A[j] = *(const float4*)(qa2L + h);
                o1B[j] = *(const float4*)(qa2L + 128 + h);
                o2A[j] = *(const float4*)(qb2L + h);
                o2B[j] = *(const float4*)(qb2L + 128 + h);
            }
            w2r[j] = *(const float4*)(p.W2 + h);
        }

        #pragma unroll
        for (int kt = 0; kt < 4; ++kt) {
            const float* __restrict__ r1 = S1g + (size_t)(bS + kt * 64 + kk) * H;
            const float* __restrict__ r2 = S2g + (size_t)(bS + kt * 64 + kk) * H;

            float4 x1[4], x2[4];
            #pragma unroll
            for (int j = 0; j < 4; ++j) {
                const int h = hh * 4 + 32 * j;
                x1[j] = *(const float4*)(r1 + h);
                x2[j] = *(const float4*)(r2 + h);
            }

            float aA = 0.f, aB = 0.f;
            #pragma unroll
            for (int j = 0; j < 4; ++j) {
                const float4 w = w2r[j];
                SC8(aA, o1A[j], x1[j], o2A[j], x2[j])
                SC8(aB, o1B[j], x1[j], o2B[j], x2[j])
            }
            #pragma unroll
            for (int o = 1; o < 8; o <<= 1) {
                aA += __shfl_xor(aA, o, 8);
                aB += __shfl_xor(aB, o, 8);
            }
            if (hh == 0) {
                const int k = kt * 64 + kk;
                s8[k]       = aA + mask[(size_t)rA * S + k] * NEGV;
                s8[256 + k] = aB + mask[(size_t)rB * S + k] * NEGV;
            }
        }
    }
    __syncthreads();

    // ---- softmax (no normalize pass): waves 0-1 own rows 0-1 ----
    {
        const int g = tid >> 6, c = tid & 63;
        if (g < 2) {
            float* rowp = s8 + g * 256;
            float m = -INFINITY;
            #pragma unroll
            for (int k = c; k < 256; k += 64) m = fmaxf(m, rowp[k]);
            for (int o = 32; o; o >>= 1) m = fmaxf(m, __shfl_xor(m, o, 64));
            float s = 0.f;
            #pragma unroll
            for (int k = c; k < 256; k += 64) { const float e = __expf(rowp[k] - m); rowp[k] = e; s += e; }
            for (int o = 32; o; o >>= 1) s += __shfl_xor(s, o, 64);
            if (c == 0) rinvS[g] = 1.f / s;
        }
    }
    __syncthreads();

    float* avp = smem + SB;          // [2][8][128]
    float* aoS = smem + SB + 2048;   // [2][128]
    float* pp  = smem + SB + 2304;   // [8][2][128]

    // ---- AV, k-split x8 (32-deep) ----
    {
        const int r = tid >> 8, t = tid & 255, kq = t >> 5, c4 = t & 31;
        const float4* V4 = (const float4*)(V + (size_t)bS * D);
        const float* sp = s8 + r * 256 + kq * 32;
        float4 acc = make_float4(0.f, 0.f, 0.f, 0.f);
        #pragma unroll 8
        for (int k = 0; k < 32; ++k) {
            const float a = sp[k];
            const float4 v = V4[(kq * 32 + k) * 32 + c4];
            acc.x = fmaf(a, v.x, acc.x); acc.y = fmaf(a, v.y, acc.y);
            acc.z = fmaf(a, v.z, acc.z); acc.w = fmaf(a, v.w, acc.w);
        }
        ((float4*)avp)[(r * 8 + kq) * 32 + c4] = acc;
    }
    __syncthreads();
    if (tid < 64) {   // reduce 8 k-partials, scale by 1/sum
        const int r = tid >> 5, c4 = tid & 31;
        float4 s0 = make_float4(0.f, 0.f, 0.f, 0.f);
        #pragma unroll
        for (int i = 0; i < 8; ++i) {
            const float4 v = ((const float4*)avp)[(r * 8 + i) * 32 + c4];
            s0.x += v.x; s0.y += v.y; s0.z += v.z; s0.w += v.w;
        }
        const float rv = rinvS[r];
        ((float4*)aoS)[r * 32 + c4] = make_float4(s0.x * rv, s0.y * rv, s0.z * rv, s0.w * rv);
    }
    __syncthreads();

    // ---- outproj, k-split x8 (16-deep) ----
    {
        const int kq = tid >> 6, unit = tid & 63, r = unit >> 5, c4 = unit & 31;
        const float4* W4 = (const float4*)Wd;
        const float* ap = aoS + r * 128 + kq * 16;
        float4 acc = make_float4(0.f, 0.f, 0.f, 0.f);
        #pragma unroll 8
        for (int k = 0; k < 16; ++k) {
            const float a = ap[k];
            const float4 w = W4[(kq * 16 + k) * 32 + c4];
            acc.x = fmaf(a, w.x, acc.x); acc.y = fmaf(a, w.y, acc.y);
            acc.z = fmaf(a, w.z, acc.z); acc.w = fmaf(a, w.w, acc.w);
        }
        ((float4*)pp)[kq * 64 + unit] = acc;
    }
    __syncthreads();

    // ---- combine + bias + residual + LN -> rowS ----
    if (tid < 64) {
        const int r = tid >> 5, c4 = tid & 31;
        float4 sum = ((const float4*)bd)[c4];
        #pragma unroll
        for (int i = 0; i < 8; ++i) {
            const float4 v = ((const float4*)pp)[i * 64 + tid];
            sum.x += v.x; sum.y += v.y; sum.z += v.z; sum.w += v.w;
        }
        float4 r4;
        if (FIRST) r4 = ((const float4*)(p.x + (size_t)(r0 + r) * 128))[c4];
        else       r4 = ((const float4*)rowS)[r * 32 + c4];
        const float x0 = sum.x + r4.x, x1 = sum.y + r4.y;
        const float x2 = sum.z + r4.z, x3 = sum.w + r4.w;
        float s  = x0 + x1 + x2 + x3;
        float s2 = x0 * x0 + x1 * x1 + x2 * x2 + x3 * x3;
        for (int o = 16; o; o >>= 1) { s += __shfl_xor(s, o, 32); s2 += __shfl_xor(s2, o, 32); }
        const float m = s * (1.f / 128), var = s2 * (1.f / 128) - m * m;
        const float rs = rsqrtf(var + LN_EPS);
        const float4 gv = ((const float4*)lg)[c4], bv = ((const float4*)lb)[c4];
        float4 o4;
        o4.x = (x0 - m) * rs * gv.x + bv.x; o4.y = (x1 - m) * rs * gv.y + bv.y;
        o4.z = (x2 - m) * rs * gv.z + bv.z; o4.w = (x3 - m) * rs * gv.w + bv.w;
        ((float4*)rowS)[r * 32 + c4] = o4;
    }
    __syncthreads();

    if (FIRST) {
        // ---- qproj: q2w = LN1out@Ww2+bw2; qa2/qb2 = q2w@{W1q,W1k}+b1 -> LDS
        float* qpp  = smem + SB;         // [8][2][128]
        float* q2wS = smem + SB + 2048;  // [2][128]
        float* qp2  = smem + SB + 2304;  // [2][4][2][128]
        {   // q2w partials, k-split x8 (16-deep)
            const int kq = tid >> 6, unit = tid & 63, r = unit >> 5, c4 = unit & 31;
            const float4* W4 = (const float4*)p.Ww2;
            const float* ap = rowS + r * 128 + kq * 16;
            float4 acc = make_float4(0.f, 0.f, 0.f, 0.f);
            #pragma unroll 8
            for (int k = 0; k < 16; ++k) {
                const float a = ap[k];
                const float4 w = W4[(kq * 16 + k) * 32 + c4];
                acc.x = fmaf(a, w.x, acc.x); acc.y = fmaf(a, w.y, acc.y);
                acc.z = fmaf(a, w.z, acc.z); acc.w = fmaf(a, w.w, acc.w);
            }
            ((float4*)qpp)[kq * 64 + unit] = acc;
        }
        __syncthreads();
        if (tid < 64) {
            const int c4 = tid & 31;
            float4 sum = ((const float4*)p.bw2)[c4];
            #pragma unroll
            for (int i = 0; i < 8; ++i) {
                const float4 v = ((const float4*)qpp)[i * 64 + tid];
                sum.x += v.x; sum.y += v.y; sum.z += v.z; sum.w += v.w;
            }
            ((float4*)q2wS)[tid] = sum;
        }
        __syncthreads();
        {   // qa2 = q2w@W1q + b1 ; qb2 = q2w@W1k + b1 ; k-split x4 (32-deep)
            const int which = tid >> 8, sub = tid & 255;
            const int kh = sub >> 6, unit2 = sub & 63, r = unit2 >> 5, c4 = unit2 & 31;
            const float4* W4 = (const float4*)(which ? p.W1k : p.W1q);
            const float* ap = q2wS + r * 128 + kh * 32;
            float4 acc = make_float4(0.f, 0.f, 0.f, 0.f);
            #pragma unroll 8
            for (int k = 0; k < 32; ++k) {
                const float a = ap[k];
                const float4 w = W4[(kh * 32 + k) * 32 + c4];
                acc.x = fmaf(a, w.x, acc.x); acc.y = fmaf(a, w.y, acc.y);
                acc.z = fmaf(a, w.z, acc.z); acc.w = fmaf(a, w.w, acc.w);
            }
            ((float4*)qp2)[(which * 4 + kh) * 64 + unit2] = acc;
        }
        __syncthreads();
        if (tid < 128) {   // reduce 4 k-splits + b1 -> qa2L/qb2L
            const int which = tid >> 6, unit2 = tid & 63, c4 = unit2 & 31;
            float4 sum = ((const float4*)p.b1)[c4];
            #pragma unroll
            for (int i = 0; i < 4; ++i) {
                const float4 v = ((const float4*)qp2)[(which * 4 + i) * 64 + unit2];
                sum.x += v.x; sum.y += v.y; sum.z += v.z; sum.w += v.w;
            }
            float* oq = which ? qb2L : qa2L;
            ((float4*)oq)[unit2] = sum;
        }
        __syncthreads();
    } else {
        // ---- FFN + LN3 -> out ----
        float* hidP = smem + SB;         // [4kh][2r][512]; [0,1024) -> hidden
        float* part = smem + SB + 4096;  // [16kg][2r][128]
        {   // ffn1: f4-col c of 128, k-quarter kh (32-deep); 2-row accs
            const int c = tid & 127, kh = tid >> 7;
            const float4* Wf1_4 = (const float4*)p.Wf1;
            float4 a0 = make_float4(0.f,0.f,0.f,0.f), a1 = a0;
            const int kbase = kh * 32;
            #pragma unroll 8
            for (int k = 0; k < 32; ++k) {
                const int kk = kbase + k;
                const float4 w = Wf1_4[kk * 128 + c];
                const float s0 = rowS[kk], s1 = rowS[128 + kk];
                a0.x=fmaf(s0,w.x,a0.x); a0.y=fmaf(s0,w.y,a0.y); a0.z=fmaf(s0,w.z,a0.z); a0.w=fmaf(s0,w.w,a0.w);
                a1.x=fmaf(s1,w.x,a1.x); a1.y=fmaf(s1,w.y,a1.y); a1.z=fmaf(s1,w.z,a1.z); a1.w=fmaf(s1,w.w,a1.w);
            }
            float4* h4 = (float4*)hidP;
            h4[kh * 256 + c]       = a0;
            h4[kh * 256 + 128 + c] = a1;
        }
        __syncthreads();
        for (int i = tid; i < 1024; i += 512) {   // reduce 4 k-quarters + relu
            hidP[i] = fmaxf(hidP[i] + hidP[1024 + i] + hidP[2048 + i] + hidP[3072 + i]
                            + p.bf1[i & 511], 0.f);
        }
        __syncthreads();
        {   // ffn2: c4f of 32, k-group kg (16 x 32); 2-row accs
            const int c4f = tid & 31, kg = tid >> 5;
            const float4* Wf2_4 = (const float4*)p.Wf2;
            float4 a0 = make_float4(0.f,0.f,0.f,0.f), a1 = a0;
            const int kbase = kg * 32;
            const float* h0 = hidP + kbase;
            const float* h1 = hidP + 512 + kbase;
            #pragma unroll 8
            for (int k = 0; k < 32; ++k) {
                const float4 w = Wf2_4[(kbase + k) * 32 + c4f];
                const float s0 = h0[k], s1 = h1[k];
                a0.x=fmaf(s0,w.x,a0.x); a0.y=fmaf(s0,w.y,a0.y); a0.z=fmaf(s0,w.z,a0.z); a0.w=fmaf(s0,w.w,a0.w);
                a1.x=fmaf(s1,w.x,a1.x); a1.y=fmaf(s1,w.y,a1.y); a1.z=fmaf(s1,w.z,a1.z); a1.w=fmaf(s1,w.w,a1.w);
            }
            float4* p4 = (float4*)part;
            p4[kg * 64 + c4f]      = a0;
            p4[kg * 64 + 32 + c4f] = a1;
        }
        __syncthreads();
        if (tid < 64) {  // reduce 16 k-partials + bias + residual + LN3 -> out
            const int r = tid >> 5, c4 = tid & 31;
            float4 sum = ((const float4*)p.bf2)[c4];
            #pragma unroll
            for (int kg = 0; kg < 16; ++kg) {
                const float4 v = ((const float4*)part)[kg * 64 + r * 32 + c4];
                sum.x += v.x; sum.y += v.y; sum.z += v.z; sum.w += v.w;
            }
            const float4 r4 = ((const float4*)rowS)[r * 32 + c4];
            const float x0 = sum.x + r4.x, x1 = sum.y + r4.y;
            const float x2 = sum.z + r4.z, x3 = sum.w + r4.w;
            float s  = x0 + x1 + x2 + x3;
            float s2 = x0 * x0 + x1 * x1 + x2 * x2 + x3 * x3;
            for (int o = 16; o; o >>= 1) { s += __shfl_xor(s, o, 32); s2 += __shfl_xor(s2, o, 32); }
            const float m = s * (1.f / 128), var = s2 * (1.f / 128) - m * m;
            const float rs = rsqrtf(var + LN_EPS);
            const float4 gv = ((const float4*)p.ln3g)[c4], bv = ((const float4*)p.ln3b)[c4];
            float4 o4;
            o4.x = (x0 - m) * rs * gv.x + bv.x; o4.y = (x1 - m) * rs * gv.y + bv.y;
            o4.z = (x2 - m) * rs * gv.z + bv.z; o4.w = (x3 - m) * rs * gv.w + bv.w;
            ((float4*)p.out)[(size_t)(r0 + r) * 32 + c4] = o4;
        }
    }
}

// ================= 2: fused attn1 + attn2, grid R/2 = 512 ==================
__global__ __launch_bounds__(512) void fused_attn12_kernel(P p)
{
    __shared__ __align__(16) float smem[9488];
    const int tid = threadIdx.x;
    const int r0 = blockIdx.x * 2, bS = (r0 >> 8) * S;
    attn_stage<true >(p, smem, tid, r0, bS);
    attn_stage<false>(p, smem, tid, r0, bS);
}

extern "C" void kernel_launch(void* const* d_in, const int* in_sizes, int n_in,
                              void* d_out, int out_size, void* d_ws, size_t ws_size,
                              hipStream_t stream) {
    (void)in_sizes; (void)n_in; (void)out_size; (void)ws_size;
    P p;
    p.x        = (const float*)d_in[0];
    p.enc      = (const float*)d_in[1];
    p.com_mask = (const float*)d_in[2];
    p.dec_mask = (const float*)d_in[3];
    p.W1q = (const float*)d_in[4];
    p.W1k = (const float*)d_in[5];
    p.b1  = (const float*)d_in[6];
    p.W2  = (const float*)d_in[7];
    // d_in[8] = b2: per-row constant -> dropped (softmax shift invariance)
    p.Ww1 = (const float*)d_in[9];
    p.bw1 = (const float*)d_in[10];
    p.Wd1 = (const float*)d_in[11];
    p.bd1 = (const float*)d_in[12];
    p.Ww2 = (const float*)d_in[13];
    p.bw2 = (const float*)d_in[14];
    p.Wd2 = (const float*)d_in[15];
    p.bd2 = (const float*)d_in[16];
    p.Wf1 = (const float*)d_in[17];
    p.bf1 = (const float*)d_in[18];
    p.Wf2 = (const float*)d_in[19];
    p.bf2 = (const float*)d_in[20];
    p.ln1g = (const float*)d_in[21];
    p.ln1b = (const float*)d_in[22];
    p.ln2g = (const float*)d_in[23];
    p.ln2b = (const float*)d_in[24];
    p.ln3g = (const float*)d_in[25];
    p.ln3b = (const float*)d_in[26];
    p.out  = (float*)d_out;

    float* ws = (float*)d_ws;
    const size_t RD = (size_t)R * D;      // 131072
    p.xw    = ws;
    p.qa    = p.xw    + RD;
    p.kb    = p.qa    + RD;
    p.kv2w  = p.kb    + RD;
    p.kb2   = p.kv2w  + RD;
    p.ka2   = p.kb2   + RD;

    proj3_kernel<<<dim3(R / 4, 2), 512, 0, stream>>>(p);
    fused_attn12_kernel<<<R / 2, 512, 0, stream>>>(p);
}